// Round 1
// baseline (1553.956 us; speedup 1.0000x reference)
//
#include <hip/hip_runtime.h>
#include <math.h>

// AnyNet stereo forward, fp32, correctness-first.
// Shapes: B=8, C=8 feature channels.
// stage0: H=32,W=80,D=12,CH=16 ; stage1: H=64,W=160,S=5,CH=4 ; stage2: H=128,W=320,S=5,CH=4
// full-res output: 512 x 1280, out = [pred0, pred1, pred2, depth] fp32.

#define FULL_H 512
#define FULL_W 1280
#define NB 8
#define NPIX (NB * FULL_H * FULL_W)   // 5,242,880

// ---------------- stage-0 L1 cost volume ----------------
__global__ __launch_bounds__(256) void cost0_k(const float* __restrict__ fl,
                                               const float* __restrict__ fr,
                                               float* __restrict__ cost) {
    const int H = 32, W = 80, D = 12, C = 8;
    int idx = blockIdx.x * 256 + threadIdx.x;
    int total = NB * D * H * W;
    if (idx >= total) return;
    int w = idx % W; int t = idx / W;
    int h = t % H; t /= H;
    int d = t % D; int b = t / D;
    int src = w - d;
    float acc = 0.f;
    for (int c = 0; c < C; ++c) {
        int base = ((b * C + c) * H + h) * W;
        float flv = fl[base + w];
        float frv = (src >= 0) ? fr[base + src] : 0.f;
        acc += fabsf(flv - frv);
    }
    cost[((b * D + d) * H + h) * W + w] = acc;
}

// ---------------- residual (warped) cost volume, S=5 shifts -2..2 ----------------
__global__ __launch_bounds__(256) void costres_k(const float* __restrict__ fl,
                                                 const float* __restrict__ fr,
                                                 const float* __restrict__ wf,
                                                 float* __restrict__ cost,
                                                 int H, int W) {
    const int C = 8, S = 5;
    int idx = blockIdx.x * 256 + threadIdx.x;
    int total = NB * S * H * W;
    if (idx >= total) return;
    int w = idx % W; int t = idx / W;
    int h = t % H; t /= H;
    int s = t % S; int b = t / S;
    float disp  = wf[(b * H + h) * W + w];
    float shift = (float)(s - 2);
    float xs  = (float)w - (disp - shift);
    float x0f = floorf(xs);
    float w1  = xs - x0f;                       // frac from TRUE floor
    float x0fc = fminf(fmaxf(x0f, -2.f), (float)W); // clamp only for int safety
    int x0 = (int)x0fc;
    int x1 = x0 + 1;
    float m0 = (x0 >= 0 && x0 <= W - 1) ? (1.f - w1) : 0.f;
    float m1 = (x1 >= 0 && x1 <= W - 1) ? w1 : 0.f;
    int x0c = min(max(x0, 0), W - 1);
    int x1c = min(max(x1, 0), W - 1);
    float acc = 0.f;
    const float* flb = fl + ((b * C) * H + h) * W;
    const float* frb = fr + ((b * C) * H + h) * W;
    int cs = H * W * C; (void)cs;
    for (int c = 0; c < C; ++c) {
        float v = frb[x0c] * m0 + frb[x1c] * m1;
        acc += fabsf(flb[w] - v);
        flb += H * W * 1;  // next channel: stride H*W within [B,C,H,W] after b,c folding
        frb += H * W * 1;
    }
    cost[idx] = acc;
}

// ---------------- generic 3x3x3 SAME conv3d ----------------
// x: [B, CIN, D, H, W]  w(global): [COUT, CIN, 27]  y: [B, COUT, D, H, W]
// LDS layout transposed: wl[(ci*27 + tap)*COUT + co]  (co contiguous -> float4 broadcast)
template <int CIN, int COUT, bool RELU>
__global__ __launch_bounds__(256) void conv3d_k(const float* __restrict__ x,
                                                const float* __restrict__ wg,
                                                float* __restrict__ y,
                                                int total, int D, int H, int W) {
    __shared__ __align__(16) float wl[CIN * 27 * COUT];
    for (int i = threadIdx.x; i < CIN * 27 * COUT; i += 256) {
        int co = i % COUT; int rest = i / COUT;
        int tap = rest % 27; int ci = rest / 27;
        wl[i] = wg[(co * CIN + ci) * 27 + tap];
    }
    __syncthreads();
    int idx = blockIdx.x * 256 + threadIdx.x;
    if (idx >= total) return;
    int w = idx % W; int t = idx / W;
    int h = t % H; t /= H;
    int d = t % D; int b = t / D;
    float acc[COUT];
#pragma unroll
    for (int i = 0; i < COUT; ++i) acc[i] = 0.f;
    const int chs = D * H * W;
    const float* xb = x + b * CIN * chs + (d * H + h) * W + w;  // centered
    for (int ci = 0; ci < CIN; ++ci) {
        const float* xc = xb + ci * chs;
#pragma unroll
        for (int kd = 0; kd < 3; ++kd) {
            int dd = d + kd - 1; if (dd < 0 || dd >= D) continue;
#pragma unroll
            for (int kh = 0; kh < 3; ++kh) {
                int hh = h + kh - 1; if (hh < 0 || hh >= H) continue;
#pragma unroll
                for (int kw = 0; kw < 3; ++kw) {
                    int ww = w + kw - 1; if (ww < 0 || ww >= W) continue;
                    float xv = xc[((kd - 1) * H + (kh - 1)) * W + (kw - 1)];
                    const int tap = kd * 9 + kh * 3 + kw;
                    const float* wp = &wl[(ci * 27 + tap) * COUT];
                    if constexpr (COUT == 1) {
                        acc[0] = fmaf(xv, wp[0], acc[0]);
                    } else {
#pragma unroll
                        for (int q = 0; q < COUT / 4; ++q) {
                            float4 wq = reinterpret_cast<const float4*>(wp)[q];
                            acc[q * 4 + 0] = fmaf(xv, wq.x, acc[q * 4 + 0]);
                            acc[q * 4 + 1] = fmaf(xv, wq.y, acc[q * 4 + 1]);
                            acc[q * 4 + 2] = fmaf(xv, wq.z, acc[q * 4 + 2]);
                            acc[q * 4 + 3] = fmaf(xv, wq.w, acc[q * 4 + 3]);
                        }
                    }
                }
            }
        }
    }
    int outbase = b * COUT * chs + (d * H + h) * W + w;
#pragma unroll
    for (int co = 0; co < COUT; ++co) {
        float v = acc[co];
        if (RELU) v = fmaxf(v, 0.f);
        y[outbase + co * chs] = v;
    }
}

// ---------------- softargmin disparity regression ----------------
// cost: [B, D, H, W]; out: [B, H*W];  d = (sum softmax(-cost)*dval) * scale
__global__ __launch_bounds__(256) void dispreg_k(const float* __restrict__ cost,
                                                 float* __restrict__ dsm,
                                                 int total, int D, int HW,
                                                 float dstart, float scale) {
    int idx = blockIdx.x * 256 + threadIdx.x;
    if (idx >= total) return;
    int hw = idx % HW; int b = idx / HW;
    const float* c = cost + b * D * HW + hw;
    float m = -1e30f;
    for (int d = 0; d < D; ++d) m = fmaxf(m, -c[d * HW]);
    float s = 0.f, ws = 0.f;
    for (int d = 0; d < D; ++d) {
        float e = expf(-c[d * HW] - m);
        s += e;
        ws = fmaf(e, dstart + (float)d, ws);
    }
    dsm[idx] = ws / s * scale;
}

// ---------------- bilinear upsample (jax half-pixel, clamped) + optional residual add ----------------
__global__ __launch_bounds__(256) void upsample_add_k(const float* __restrict__ s,
                                                      int sh, int sw,
                                                      const float* __restrict__ prev,
                                                      float* __restrict__ out) {
    int idx = blockIdx.x * 256 + threadIdx.x;
    if (idx >= NPIX) return;
    int x = idx % FULL_W; int t = idx / FULL_W;
    int y = t % FULL_H; int b = t / FULL_H;
    float fy = (y + 0.5f) * ((float)sh / FULL_H) - 0.5f;
    float fx = (x + 0.5f) * ((float)sw / FULL_W) - 0.5f;
    int y0 = (int)floorf(fy); float wy = fy - (float)y0;
    int x0 = (int)floorf(fx); float wx = fx - (float)x0;
    int y0c = min(max(y0, 0), sh - 1), y1c = min(max(y0 + 1, 0), sh - 1);
    int x0c = min(max(x0, 0), sw - 1), x1c = min(max(x0 + 1, 0), sw - 1);
    const float* sb = s + b * sh * sw;
    float v00 = sb[y0c * sw + x0c], v01 = sb[y0c * sw + x1c];
    float v10 = sb[y1c * sw + x0c], v11 = sb[y1c * sw + x1c];
    float v = (1.f - wy) * ((1.f - wx) * v00 + wx * v01) +
              wy        * ((1.f - wx) * v10 + wx * v11);
    if (prev) v += prev[idx];
    out[idx] = v;
}

// ---------------- antialiased triangle downsample (jax resize antialias=True) + scale ----------------
// in: [B, 512, 1280] (a pred slice); out: [B, oh, ow]; factor f per dim; out *= scale
__global__ __launch_bounds__(256) void wflow_k(const float* __restrict__ pred,
                                               float* __restrict__ wf,
                                               int oh, int ow, int f, float scale) {
    int idx = blockIdx.x * 256 + threadIdx.x;
    int total = NB * oh * ow;
    if (idx >= total) return;
    int ox = idx % ow; int t = idx / ow;
    int oy = t % oh; int b = t / oh;
    float ff = (float)f, invf = 1.f / (float)f;
    float cy = (oy + 0.5f) * ff - 0.5f;
    float cx = (ox + 0.5f) * ff - 0.5f;
    int ylo = max((int)ceilf(cy - ff), 0);
    int yhi = min((int)floorf(cy + ff), FULL_H - 1);
    int xlo = max((int)ceilf(cx - ff), 0);
    int xhi = min((int)floorf(cx + ff), FULL_W - 1);
    const float* pb = pred + b * FULL_H * FULL_W;
    float acc = 0.f, wys = 0.f, wxs = 0.f;
    for (int iy = ylo; iy <= yhi; ++iy) {
        float wy = 1.f - fabsf((float)iy - cy) * invf;
        wys += wy;
        float rowacc = 0.f;
        const float* row = pb + iy * FULL_W;
        for (int ix = xlo; ix <= xhi; ++ix) {
            float wx = 1.f - fabsf((float)ix - cx) * invf;
            rowacc = fmaf(wx, row[ix], rowacc);
        }
        acc = fmaf(wy, rowacc, acc);
    }
    for (int ix = xlo; ix <= xhi; ++ix) wxs += 1.f - fabsf((float)ix - cx) * invf;
    wf[idx] = acc / (wys * wxs) * scale;
}

// ---------------- depth from pred0 ----------------
__global__ __launch_bounds__(256) void depth_k(const float* __restrict__ pred0,
                                               float* __restrict__ depth) {
    int idx = blockIdx.x * 256 + threadIdx.x;
    if (idx >= NPIX) return;
    float p = fabsf(pred0[idx]);
    float d = 64.f / p;                      // BASELINE*FOCAL = 0.2*320
    if (isnan(d)) d = 100.f;                 // nan_to_num(nan=MAX_DEPTH)
    d = fminf(fmaxf(d, 0.1f), 100.f);        // clip (posinf -> 100 via fminf)
    depth[idx] = d;
}

static inline dim3 g(int n) { return dim3((n + 255) / 256); }

extern "C" void kernel_launch(void* const* d_in, const int* in_sizes, int n_in,
                              void* d_out, int out_size, void* d_ws, size_t ws_size,
                              hipStream_t stream) {
    const float* f_l0  = (const float*)d_in[0];
    const float* f_r0  = (const float*)d_in[1];
    const float* f_l1  = (const float*)d_in[2];
    const float* f_r1  = (const float*)d_in[3];
    const float* f_l2  = (const float*)d_in[4];
    const float* f_r2  = (const float*)d_in[5];
    const float* w_in0  = (const float*)d_in[6];
    const float* w_mid0 = (const float*)d_in[7];
    const float* w_out0 = (const float*)d_in[8];
    const float* w_in1  = (const float*)d_in[9];
    const float* w_mid1 = (const float*)d_in[10];
    const float* w_out1 = (const float*)d_in[11];
    const float* w_in2  = (const float*)d_in[12];
    const float* w_mid2 = (const float*)d_in[13];
    const float* w_out2 = (const float*)d_in[14];

    float* out   = (float*)d_out;
    float* pred0 = out;
    float* pred1 = out + NPIX;
    float* pred2 = out + 2 * NPIX;
    float* depth = out + 3 * NPIX;

    float* ws   = (float*)d_ws;
    float* xA   = ws;                 // 6,553,600 floats (max conv buf: 8*4*5*128*320)
    float* xB   = xA + 6553600;       // 6,553,600
    float* cost = xB + 6553600;       // 1,638,400 (max cost vol: 8*5*128*320)
    float* dsm  = cost + 1638400;     // 327,680
    float* wfl  = dsm + 327680;       // 327,680

    dim3 blk(256);

    // ---------------- stage 0 ----------------
    {
        const int D = 12, H = 32, W = 80;
        const int total = NB * D * H * W;
        cost0_k<<<g(total), blk, 0, stream>>>(f_l0, f_r0, cost);
        conv3d_k<1, 16, true><<<g(total), blk, 0, stream>>>(cost, w_in0, xA, total, D, H, W);
        const float* src = xA; float* dst = xB;
        for (int k = 0; k < 4; ++k) {
            conv3d_k<16, 16, true><<<g(total), blk, 0, stream>>>(src, w_mid0 + k * 16 * 16 * 27, dst, total, D, H, W);
            const float* ns = dst; dst = (float*)src; src = ns;
        }
        conv3d_k<16, 1, false><<<g(total), blk, 0, stream>>>(src, w_out0, cost, total, D, H, W);
        dispreg_k<<<g(NB * H * W), blk, 0, stream>>>(cost, dsm, NB * H * W, D, H * W, 0.f, 16.f);
        upsample_add_k<<<g(NPIX), blk, 0, stream>>>(dsm, H, W, nullptr, pred0);
    }

    // ---------------- stage 1 ----------------
    {
        const int D = 5, H = 64, W = 160;
        const int total = NB * D * H * W;
        wflow_k<<<g(NB * H * W), blk, 0, stream>>>(pred0, wfl, H, W, 8, 0.125f);
        costres_k<<<g(total), blk, 0, stream>>>(f_l1, f_r1, wfl, cost, H, W);
        conv3d_k<1, 4, true><<<g(total), blk, 0, stream>>>(cost, w_in1, xA, total, D, H, W);
        const float* src = xA; float* dst = xB;
        for (int k = 0; k < 4; ++k) {
            conv3d_k<4, 4, true><<<g(total), blk, 0, stream>>>(src, w_mid1 + k * 4 * 4 * 27, dst, total, D, H, W);
            const float* ns = dst; dst = (float*)src; src = ns;
        }
        conv3d_k<4, 1, false><<<g(total), blk, 0, stream>>>(src, w_out1, cost, total, D, H, W);
        dispreg_k<<<g(NB * H * W), blk, 0, stream>>>(cost, dsm, NB * H * W, D, H * W, -2.f, 8.f);
        upsample_add_k<<<g(NPIX), blk, 0, stream>>>(dsm, H, W, pred0, pred1);
    }

    // ---------------- stage 2 ----------------
    {
        const int D = 5, H = 128, W = 320;
        const int total = NB * D * H * W;
        wflow_k<<<g(NB * H * W), blk, 0, stream>>>(pred1, wfl, H, W, 4, 0.25f);
        costres_k<<<g(total), blk, 0, stream>>>(f_l2, f_r2, wfl, cost, H, W);
        conv3d_k<1, 4, true><<<g(total), blk, 0, stream>>>(cost, w_in2, xA, total, D, H, W);
        const float* src = xA; float* dst = xB;
        for (int k = 0; k < 4; ++k) {
            conv3d_k<4, 4, true><<<g(total), blk, 0, stream>>>(src, w_mid2 + k * 4 * 4 * 27, dst, total, D, H, W);
            const float* ns = dst; dst = (float*)src; src = ns;
        }
        conv3d_k<4, 1, false><<<g(total), blk, 0, stream>>>(src, w_out2, cost, total, D, H, W);
        dispreg_k<<<g(NB * H * W), blk, 0, stream>>>(cost, dsm, NB * H * W, D, H * W, -2.f, 4.f);
        upsample_add_k<<<g(NPIX), blk, 0, stream>>>(dsm, H, W, pred1, pred2);
    }

    depth_k<<<g(NPIX), blk, 0, stream>>>(pred0, depth);
}

// Round 2
// 1045.911 us; speedup vs baseline: 1.4857x; 1.4857x over previous
//
#include <hip/hip_runtime.h>
#include <math.h>

// AnyNet stereo forward, fp32. Round 2: register-blocked conv3d (w-strip per
// thread, all COUT accumulated in regs, LDS float4 weight broadcasts).

#define FULL_H 512
#define FULL_W 1280
#define NB 8
#define NPIX (NB * FULL_H * FULL_W)   // 5,242,880

// ---------------- stage-0 L1 cost volume ----------------
__global__ __launch_bounds__(256) void cost0_k(const float* __restrict__ fl,
                                               const float* __restrict__ fr,
                                               float* __restrict__ cost) {
    const int H = 32, W = 80, D = 12, C = 8;
    int idx = blockIdx.x * 256 + threadIdx.x;
    int total = NB * D * H * W;
    if (idx >= total) return;
    int w = idx % W; int t = idx / W;
    int h = t % H; t /= H;
    int d = t % D; int b = t / D;
    int src = w - d;
    float acc = 0.f;
    for (int c = 0; c < C; ++c) {
        int base = ((b * C + c) * H + h) * W;
        float flv = fl[base + w];
        float frv = (src >= 0) ? fr[base + src] : 0.f;
        acc += fabsf(flv - frv);
    }
    cost[((b * D + d) * H + h) * W + w] = acc;
}

// ---------------- residual (warped) cost volume, S=5 shifts -2..2 ----------------
__global__ __launch_bounds__(256) void costres_k(const float* __restrict__ fl,
                                                 const float* __restrict__ fr,
                                                 const float* __restrict__ wf,
                                                 float* __restrict__ cost,
                                                 int H, int W) {
    const int C = 8, S = 5;
    int idx = blockIdx.x * 256 + threadIdx.x;
    int total = NB * S * H * W;
    if (idx >= total) return;
    int w = idx % W; int t = idx / W;
    int h = t % H; t /= H;
    int s = t % S; int b = t / S;
    float disp  = wf[(b * H + h) * W + w];
    float shift = (float)(s - 2);
    float xs  = (float)w - (disp - shift);
    float x0f = floorf(xs);
    float w1  = xs - x0f;
    float x0fc = fminf(fmaxf(x0f, -2.f), (float)W);
    int x0 = (int)x0fc;
    int x1 = x0 + 1;
    float m0 = (x0 >= 0 && x0 <= W - 1) ? (1.f - w1) : 0.f;
    float m1 = (x1 >= 0 && x1 <= W - 1) ? w1 : 0.f;
    int x0c = min(max(x0, 0), W - 1);
    int x1c = min(max(x1, 0), W - 1);
    float acc = 0.f;
    const float* flb = fl + ((b * C) * H + h) * W;
    const float* frb = fr + ((b * C) * H + h) * W;
    for (int c = 0; c < C; ++c) {
        float v = frb[x0c] * m0 + frb[x1c] * m1;
        acc += fabsf(flb[w] - v);
        flb += H * W;
        frb += H * W;
    }
    cost[idx] = acc;
}

// ---------------- register-blocked 3x3x3 SAME conv3d ----------------
// x: [B,CIN,D,H,W]  wg: [COUT,CIN,27]  y: [B,COUT,D,H,W]
// Each thread computes WT consecutive w outputs for all COUT channels.
// Requires W % WT == 0 and W % 4 == 0 (float4-aligned strips).
// LDS weights transposed: wl[(ci*27+tap)*COUT + co]  (broadcast float4 reads)
template <int CIN, int COUT, int WT, bool RELU>
__global__ __launch_bounds__(256) void conv2_k(const float* __restrict__ x,
                                               const float* __restrict__ wg,
                                               float* __restrict__ y,
                                               int D, int H, int W, int nstrips) {
    __shared__ __align__(16) float wl[CIN * 27 * COUT];
    for (int i = threadIdx.x; i < CIN * 27 * COUT; i += 256) {
        int co = i % COUT; int rest = i / COUT;
        int tap = rest % 27; int ci = rest / 27;
        wl[i] = wg[(co * CIN + ci) * 27 + tap];
    }
    __syncthreads();

    int idx = blockIdx.x * 256 + threadIdx.x;
    if (idx >= nstrips) return;
    const int SW = W / WT;
    int sw = idx % SW; int t = idx / SW;
    int h = t % H; t /= H;
    int d = t % D; int b = t / D;
    const int wbase = sw * WT;
    const int chs = D * H * W;

    float acc[COUT][WT];
#pragma unroll
    for (int co = 0; co < COUT; ++co)
#pragma unroll
        for (int wt = 0; wt < WT; ++wt) acc[co][wt] = 0.f;

    const bool has_lo = (wbase > 0);
    const bool has_hi = (wbase + WT < W);
    const float* xb = x + (size_t)b * CIN * chs;

    for (int ci = 0; ci < CIN; ++ci) {
        const float* xc = xb + ci * chs;
#pragma unroll
        for (int kd = 0; kd < 3; ++kd) {
            int dd = d + kd - 1; if (dd < 0 || dd >= D) continue;
#pragma unroll
            for (int kh = 0; kh < 3; ++kh) {
                int hh = h + kh - 1; if (hh < 0 || hh >= H) continue;
                const float* row = xc + (dd * H + hh) * W + wbase;
                float xr[WT + 2];
#pragma unroll
                for (int j = 0; j < WT / 4; ++j) {
                    float4 v = *reinterpret_cast<const float4*>(row + j * 4);
                    xr[1 + j * 4 + 0] = v.x; xr[1 + j * 4 + 1] = v.y;
                    xr[1 + j * 4 + 2] = v.z; xr[1 + j * 4 + 3] = v.w;
                }
                xr[0]      = has_lo ? row[-1] : 0.f;
                xr[WT + 1] = has_hi ? row[WT] : 0.f;
                const int tapbase = ci * 27 + kd * 9 + kh * 3;
#pragma unroll
                for (int kw = 0; kw < 3; ++kw) {
                    const float* wp = &wl[(tapbase + kw) * COUT];
                    if constexpr (COUT == 1) {
                        float wv = wp[0];
#pragma unroll
                        for (int wt = 0; wt < WT; ++wt)
                            acc[0][wt] = fmaf(xr[wt + kw], wv, acc[0][wt]);
                    } else {
                        float4 w4[COUT / 4];
#pragma unroll
                        for (int q = 0; q < COUT / 4; ++q)
                            w4[q] = reinterpret_cast<const float4*>(wp)[q];
#pragma unroll
                        for (int wt = 0; wt < WT; ++wt) {
                            float xv = xr[wt + kw];
#pragma unroll
                            for (int q = 0; q < COUT / 4; ++q) {
                                acc[q * 4 + 0][wt] = fmaf(xv, w4[q].x, acc[q * 4 + 0][wt]);
                                acc[q * 4 + 1][wt] = fmaf(xv, w4[q].y, acc[q * 4 + 1][wt]);
                                acc[q * 4 + 2][wt] = fmaf(xv, w4[q].z, acc[q * 4 + 2][wt]);
                                acc[q * 4 + 3][wt] = fmaf(xv, w4[q].w, acc[q * 4 + 3][wt]);
                            }
                        }
                    }
                }
            }
        }
    }

    float* yb = y + (size_t)b * COUT * chs + (d * H + h) * W + wbase;
#pragma unroll
    for (int co = 0; co < COUT; ++co) {
#pragma unroll
        for (int j = 0; j < WT / 4; ++j) {
            float4 v;
            v.x = acc[co][j * 4 + 0]; v.y = acc[co][j * 4 + 1];
            v.z = acc[co][j * 4 + 2]; v.w = acc[co][j * 4 + 3];
            if (RELU) {
                v.x = fmaxf(v.x, 0.f); v.y = fmaxf(v.y, 0.f);
                v.z = fmaxf(v.z, 0.f); v.w = fmaxf(v.w, 0.f);
            }
            *reinterpret_cast<float4*>(yb + co * chs + j * 4) = v;
        }
    }
}

// ---------------- softargmin disparity regression ----------------
__global__ __launch_bounds__(256) void dispreg_k(const float* __restrict__ cost,
                                                 float* __restrict__ dsm,
                                                 int total, int D, int HW,
                                                 float dstart, float scale) {
    int idx = blockIdx.x * 256 + threadIdx.x;
    if (idx >= total) return;
    int hw = idx % HW; int b = idx / HW;
    const float* c = cost + b * D * HW + hw;
    float m = -1e30f;
    for (int d = 0; d < D; ++d) m = fmaxf(m, -c[d * HW]);
    float s = 0.f, ws = 0.f;
    for (int d = 0; d < D; ++d) {
        float e = expf(-c[d * HW] - m);
        s += e;
        ws = fmaf(e, dstart + (float)d, ws);
    }
    dsm[idx] = ws / s * scale;
}

// ---------------- bilinear upsample (jax half-pixel, clamped) + optional residual ----------------
__global__ __launch_bounds__(256) void upsample_add_k(const float* __restrict__ s,
                                                      int sh, int sw,
                                                      const float* __restrict__ prev,
                                                      float* __restrict__ out) {
    int idx = blockIdx.x * 256 + threadIdx.x;
    if (idx >= NPIX) return;
    int x = idx % FULL_W; int t = idx / FULL_W;
    int y = t % FULL_H; int b = t / FULL_H;
    float fy = (y + 0.5f) * ((float)sh / FULL_H) - 0.5f;
    float fx = (x + 0.5f) * ((float)sw / FULL_W) - 0.5f;
    int y0 = (int)floorf(fy); float wy = fy - (float)y0;
    int x0 = (int)floorf(fx); float wx = fx - (float)x0;
    int y0c = min(max(y0, 0), sh - 1), y1c = min(max(y0 + 1, 0), sh - 1);
    int x0c = min(max(x0, 0), sw - 1), x1c = min(max(x0 + 1, 0), sw - 1);
    const float* sb = s + b * sh * sw;
    float v00 = sb[y0c * sw + x0c], v01 = sb[y0c * sw + x1c];
    float v10 = sb[y1c * sw + x0c], v11 = sb[y1c * sw + x1c];
    float v = (1.f - wy) * ((1.f - wx) * v00 + wx * v01) +
              wy        * ((1.f - wx) * v10 + wx * v11);
    if (prev) v += prev[idx];
    out[idx] = v;
}

// ---------------- antialiased triangle downsample + scale ----------------
__global__ __launch_bounds__(256) void wflow_k(const float* __restrict__ pred,
                                               float* __restrict__ wf,
                                               int oh, int ow, int f, float scale) {
    int idx = blockIdx.x * 256 + threadIdx.x;
    int total = NB * oh * ow;
    if (idx >= total) return;
    int ox = idx % ow; int t = idx / ow;
    int oy = t % oh; int b = t / oh;
    float ff = (float)f, invf = 1.f / (float)f;
    float cy = (oy + 0.5f) * ff - 0.5f;
    float cx = (ox + 0.5f) * ff - 0.5f;
    int ylo = max((int)ceilf(cy - ff), 0);
    int yhi = min((int)floorf(cy + ff), FULL_H - 1);
    int xlo = max((int)ceilf(cx - ff), 0);
    int xhi = min((int)floorf(cx + ff), FULL_W - 1);
    const float* pb = pred + b * FULL_H * FULL_W;
    float acc = 0.f, wys = 0.f, wxs = 0.f;
    for (int iy = ylo; iy <= yhi; ++iy) {
        float wy = 1.f - fabsf((float)iy - cy) * invf;
        wys += wy;
        float rowacc = 0.f;
        const float* row = pb + iy * FULL_W;
        for (int ix = xlo; ix <= xhi; ++ix) {
            float wx = 1.f - fabsf((float)ix - cx) * invf;
            rowacc = fmaf(wx, row[ix], rowacc);
        }
        acc = fmaf(wy, rowacc, acc);
    }
    for (int ix = xlo; ix <= xhi; ++ix) wxs += 1.f - fabsf((float)ix - cx) * invf;
    wf[idx] = acc / (wys * wxs) * scale;
}

// ---------------- depth from pred0 ----------------
__global__ __launch_bounds__(256) void depth_k(const float* __restrict__ pred0,
                                               float* __restrict__ depth) {
    int idx = blockIdx.x * 256 + threadIdx.x;
    if (idx >= NPIX) return;
    float p = fabsf(pred0[idx]);
    float d = 64.f / p;
    if (isnan(d)) d = 100.f;
    d = fminf(fmaxf(d, 0.1f), 100.f);
    depth[idx] = d;
}

static inline dim3 g(int n) { return dim3((n + 255) / 256); }

extern "C" void kernel_launch(void* const* d_in, const int* in_sizes, int n_in,
                              void* d_out, int out_size, void* d_ws, size_t ws_size,
                              hipStream_t stream) {
    const float* f_l0  = (const float*)d_in[0];
    const float* f_r0  = (const float*)d_in[1];
    const float* f_l1  = (const float*)d_in[2];
    const float* f_r1  = (const float*)d_in[3];
    const float* f_l2  = (const float*)d_in[4];
    const float* f_r2  = (const float*)d_in[5];
    const float* w_in0  = (const float*)d_in[6];
    const float* w_mid0 = (const float*)d_in[7];
    const float* w_out0 = (const float*)d_in[8];
    const float* w_in1  = (const float*)d_in[9];
    const float* w_mid1 = (const float*)d_in[10];
    const float* w_out1 = (const float*)d_in[11];
    const float* w_in2  = (const float*)d_in[12];
    const float* w_mid2 = (const float*)d_in[13];
    const float* w_out2 = (const float*)d_in[14];

    float* out   = (float*)d_out;
    float* pred0 = out;
    float* pred1 = out + NPIX;
    float* pred2 = out + 2 * NPIX;
    float* depth = out + 3 * NPIX;

    float* ws   = (float*)d_ws;
    float* xA   = ws;                 // 6,553,600 floats
    float* xB   = xA + 6553600;       // 6,553,600
    float* cost = xB + 6553600;       // 1,638,400
    float* dsm  = cost + 1638400;     // 327,680
    float* wfl  = dsm + 327680;       // 327,680

    dim3 blk(256);

    // ---------------- stage 0 ----------------
    {
        const int D = 12, H = 32, W = 80;
        const int total = NB * D * H * W;
        cost0_k<<<g(total), blk, 0, stream>>>(f_l0, f_r0, cost);
        {
            int ns = total / 4;
            conv2_k<1, 16, 4, true><<<g(ns), blk, 0, stream>>>(cost, w_in0, xA, D, H, W, ns);
            const float* src = xA; float* dst = xB;
            for (int k = 0; k < 4; ++k) {
                conv2_k<16, 16, 4, true><<<g(ns), blk, 0, stream>>>(src, w_mid0 + k * 16 * 16 * 27, dst, D, H, W, ns);
                const float* nsrc = dst; dst = (float*)src; src = nsrc;
            }
            int ns1 = total / 8;
            conv2_k<16, 1, 8, false><<<g(ns1), blk, 0, stream>>>(src, w_out0, cost, D, H, W, ns1);
        }
        dispreg_k<<<g(NB * H * W), blk, 0, stream>>>(cost, dsm, NB * H * W, D, H * W, 0.f, 16.f);
        upsample_add_k<<<g(NPIX), blk, 0, stream>>>(dsm, H, W, nullptr, pred0);
    }

    // ---------------- stage 1 ----------------
    {
        const int D = 5, H = 64, W = 160;
        const int total = NB * D * H * W;
        wflow_k<<<g(NB * H * W), blk, 0, stream>>>(pred0, wfl, H, W, 8, 0.125f);
        costres_k<<<g(total), blk, 0, stream>>>(f_l1, f_r1, wfl, cost, H, W);
        int ns = total / 8;
        conv2_k<1, 4, 8, true><<<g(ns), blk, 0, stream>>>(cost, w_in1, xA, D, H, W, ns);
        const float* src = xA; float* dst = xB;
        for (int k = 0; k < 4; ++k) {
            conv2_k<4, 4, 8, true><<<g(ns), blk, 0, stream>>>(src, w_mid1 + k * 4 * 4 * 27, dst, D, H, W, ns);
            const float* nsrc = dst; dst = (float*)src; src = nsrc;
        }
        conv2_k<4, 1, 8, false><<<g(ns), blk, 0, stream>>>(src, w_out1, cost, D, H, W, ns);
        dispreg_k<<<g(NB * H * W), blk, 0, stream>>>(cost, dsm, NB * H * W, D, H * W, -2.f, 8.f);
        upsample_add_k<<<g(NPIX), blk, 0, stream>>>(dsm, H, W, pred0, pred1);
    }

    // ---------------- stage 2 ----------------
    {
        const int D = 5, H = 128, W = 320;
        const int total = NB * D * H * W;
        wflow_k<<<g(NB * H * W), blk, 0, stream>>>(pred1, wfl, H, W, 4, 0.25f);
        costres_k<<<g(total), blk, 0, stream>>>(f_l2, f_r2, wfl, cost, H, W);
        int ns = total / 8;
        conv2_k<1, 4, 8, true><<<g(ns), blk, 0, stream>>>(cost, w_in2, xA, D, H, W, ns);
        const float* src = xA; float* dst = xB;
        for (int k = 0; k < 4; ++k) {
            conv2_k<4, 4, 8, true><<<g(ns), blk, 0, stream>>>(src, w_mid2 + k * 4 * 4 * 27, dst, D, H, W, ns);
            const float* nsrc = dst; dst = (float*)src; src = nsrc;
        }
        conv2_k<4, 1, 8, false><<<g(ns), blk, 0, stream>>>(src, w_out2, cost, D, H, W, ns);
        dispreg_k<<<g(NB * H * W), blk, 0, stream>>>(cost, dsm, NB * H * W, D, H * W, -2.f, 4.f);
        upsample_add_k<<<g(NPIX), blk, 0, stream>>>(dsm, H, W, pred1, pred2);
    }

    depth_k<<<g(NPIX), blk, 0, stream>>>(pred0, depth);
}